// Round 3
// baseline (261.549 us; speedup 1.0000x reference)
//
#include <hip/hip_runtime.h>

#define IN_F   128
#define OUTD   64
#define HOUT   256      // H*OUT
#define NEG_SLOPE 0.2f
#define BN_EPS 1e-5f
#define HB     1024     // histogram blocks — appended to k0 (pack blocks first)
#define SB     512      // scatter blocks — appended to k1 (GEMM blocks first, R10 pattern)

typedef __attribute__((ext_vector_type(8))) short bf16x8;
typedef __attribute__((ext_vector_type(4))) float f32x4;
typedef __attribute__((ext_vector_type(2))) float f32x2;

__device__ __forceinline__ unsigned short f2bf(float f) {
    union { float f; unsigned u; } v; v.f = f;
    unsigned r = (v.u + 0x7FFF + ((v.u >> 16) & 1)) >> 16;   // RNE
    return (unsigned short)r;
}
__device__ __forceinline__ float bf2f(unsigned short h) {
    union { unsigned u; float f; } v; v.u = ((unsigned)h) << 16;
    return v.f;
}
__device__ __forceinline__ float u2f(unsigned u) {
    union { unsigned u; float f; } v; v.u = u;
    return v.f;
}
__device__ __forceinline__ unsigned f2u(float f) {
    union { float f; unsigned u; } v; v.f = f;
    return v.u;
}

// fragment-order index for Btg2. Tiles (tt=0..9), j=0..3, ks=0..3, 16 cols (n15), 8 k (kk).
__device__ __forceinline__ int b2idx(int c, int k) {
    int tt, j;
    if (c < 256)      { tt = (c >> 4) & 3;                     j = c >> 6; }
    else if (c < 512) { int cc = c - 256; tt = 4 + ((cc >> 4) & 3); j = cc >> 6; }
    else if (c < 576) { int cc = c - 512; tt = 8;              j = cc >> 4; }
    else              { tt = 9;                                j = 0; }
    int n15 = c & 15;
    int ks = k >> 5, qd = (k >> 3) & 3, kk = k & 7;
    return ((((tt * 4 + j) * 4 + ks) * 64) + qd * 16 + n15) * 8 + kk;
}

// ============ K0: pack weights -> Btg2 (fragment-ordered bf16) + hist role ============
__global__ __launch_bounds__(256) void k0_pack(
    const float* __restrict__ W_fc, const float* __restrict__ W_gres,
    const float* __restrict__ W_res,
    const float* __restrict__ attn_l, const float* __restrict__ attn_r,
    unsigned short* __restrict__ Btg2,
    const int* __restrict__ dst, int* __restrict__ degree,
    int* __restrict__ rank, int E)
{
    int bid = blockIdx.x, t = threadIdx.x;
    if (bid < 288) {
        int idx = bid * 256 + t;          // c*128 + k, c < 576
        int c = idx >> 7, k = idx & 127;
        float v;
        if (c < 256)      v = W_fc[k * HOUT + c];
        else if (c < 512) v = W_gres[k * HOUT + (c - 256)];
        else              v = W_res[k * OUTD + (c - 512)];
        Btg2[b2idx(c, k)] = f2bf(v);
        return;
    }
    if (bid == 288) {
        for (int p = t; p < 512; p += 256) {
            int h = p >> 7, k = p & 127;
            float sl = 0.f, sr = 0.f;
            for (int d = 0; d < 64; ++d) {
                float wv = W_fc[k * HOUT + h * 64 + d];
                sl += wv * attn_l[h * 64 + d];
                sr += wv * attn_r[h * 64 + d];
            }
            Btg2[b2idx(576 + h, k)] = f2bf(sl);
            Btg2[b2idx(580 + h, k)] = f2bf(sr);
        }
        for (int p = t; p < 8 * 128; p += 256) {
            int c = 584 + (p >> 7), k = p & 127;
            Btg2[b2idx(c, k)] = 0;
        }
        return;
    }
    // ---- hist role: degree histogram + per-edge rank (independent of GEMM chain) ----
    int ht = (bid - 289) * 256 + t;
    for (int e = ht; e < E; e += HB * 256)
        rank[e] = atomicAdd(degree + dst[e], 1);
}

// ============ K1: GEMM blocks first, scatter blocks last (role-split) ============
__global__ __launch_bounds__(256) void k1_gemm(
    const float* __restrict__ A, const unsigned short* __restrict__ Btg2,
    const float* __restrict__ gat_bias, const float* __restrict__ res_b,
    const int* __restrict__ src, const int* __restrict__ dst,
    const int* __restrict__ rank, const int* __restrict__ excl,
    const int* __restrict__ blocksum, int* __restrict__ base,
    unsigned* __restrict__ usrc_sorted,
    unsigned char* __restrict__ Hh8, unsigned char* __restrict__ Hr8,
    unsigned short* __restrict__ Rres,
    float* __restrict__ el, float* __restrict__ er,
    int N, int E, int Gblocks, int nb)
{
    int t = threadIdx.x;

    if (blockIdx.x >= Gblocks) {
        // ---- scatter role (+inline scanB; block sb==0 persists base for agg) ----
        __shared__ int sm[256];
        __shared__ int base_lds[256];
        int sb = blockIdx.x - Gblocks;
        int d0 = (t < nb) ? blocksum[t] : 0;
        sm[t] = d0; __syncthreads();
        for (int off = 1; off < 256; off <<= 1) {
            int v = (t >= off) ? sm[t - off] : 0;
            __syncthreads();
            sm[t] += v;
            __syncthreads();
        }
        base_lds[t] = sm[t] - d0;
        if (sb == 0) base[t] = sm[t] - d0;   // persist for agg
        __syncthreads();
        for (int e = sb * 256 + t; e < E; e += SB * 256) {
            int d = dst[e];
            int p = excl[d] + base_lds[d >> 8] + rank[e];
            usrc_sorted[p] = (unsigned)src[e] << 8;
        }
        return;
    }

    int w = t >> 6, lane = t & 63, quad = lane >> 4, n15 = lane & 15;
    int gw = blockIdx.x * 4 + w;
    int T = (N + 15) / 16;
    if (gw >= T) return;

    int m0 = gw * 16;
    bool full = (m0 + 16 <= N);
    int lofs = (quad * 16 + n15) * 8;

    bf16x8 af[4];
    {
        int r = m0 + n15;
#pragma unroll
        for (int ks = 0; ks < 4; ++ks) {
            float4 v0 = make_float4(0.f, 0.f, 0.f, 0.f), v1 = v0;
            if (r < N) {
                const float* ap = A + (size_t)r * IN_F + ks * 32 + quad * 8;
                v0 = *(const float4*)ap;
                v1 = *(const float4*)(ap + 4);
            }
            bf16x8 o;
            o[0] = f2bf(v0.x); o[1] = f2bf(v0.y); o[2] = f2bf(v0.z); o[3] = f2bf(v0.w);
            o[4] = f2bf(v1.x); o[5] = f2bf(v1.y); o[6] = f2bf(v1.z); o[7] = f2bf(v1.w);
            af[ks] = o;
        }
    }

    // ---- Hh: tiles 0..3 (j = head). Phase-wide load hoist: 16 frags in flight. ----
#pragma unroll
    for (int s = 0; s < 4; ++s) {
        bf16x8 bfr[4][4];
#pragma unroll
        for (int ks = 0; ks < 4; ++ks)
#pragma unroll
            for (int j = 0; j < 4; ++j)
                bfr[ks][j] = *(const bf16x8*)(Btg2 + ((s * 16 + j * 4 + ks) << 9) + lofs);
        f32x4 acc[4] = {};
#pragma unroll
        for (int ks = 0; ks < 4; ++ks)
#pragma unroll
            for (int j = 0; j < 4; ++j)
                acc[j] = __builtin_amdgcn_mfma_f32_16x16x32_bf16(af[ks], bfr[ks][j], acc[j], 0, 0, 0);
#pragma unroll
        for (int reg = 0; reg < 4; ++reg) {
            int r = m0 + quad * 4 + reg;
            if (full || r < N) {
                unsigned pk = (unsigned)__builtin_amdgcn_cvt_pk_fp8_f32(acc[0][reg], acc[1][reg], 0, false);
                pk = (unsigned)__builtin_amdgcn_cvt_pk_fp8_f32(acc[2][reg], acc[3][reg], (int)pk, true);
                *(unsigned*)(Hh8 + ((size_t)r << 8) + (s * 16 + n15) * 4) = pk;
            }
        }
    }

    // ---- Hr: tiles 4..7 (j = head) + gat_bias ----
#pragma unroll
    for (int s = 0; s < 4; ++s) {
        bf16x8 bfr[4][4];
#pragma unroll
        for (int ks = 0; ks < 4; ++ks)
#pragma unroll
            for (int j = 0; j < 4; ++j)
                bfr[ks][j] = *(const bf16x8*)(Btg2 + (((4 + s) * 16 + j * 4 + ks) << 9) + lofs);
        f32x4 acc[4] = {};
#pragma unroll
        for (int ks = 0; ks < 4; ++ks)
#pragma unroll
            for (int j = 0; j < 4; ++j)
                acc[j] = __builtin_amdgcn_mfma_f32_16x16x32_bf16(af[ks], bfr[ks][j], acc[j], 0, 0, 0);
        float b0 = gat_bias[0 * 64 + s * 16 + n15];
        float b1 = gat_bias[1 * 64 + s * 16 + n15];
        float b2 = gat_bias[2 * 64 + s * 16 + n15];
        float b3 = gat_bias[3 * 64 + s * 16 + n15];
#pragma unroll
        for (int reg = 0; reg < 4; ++reg) {
            int r = m0 + quad * 4 + reg;
            if (full || r < N) {
                unsigned pk = (unsigned)__builtin_amdgcn_cvt_pk_fp8_f32(acc[0][reg] + b0, acc[1][reg] + b1, 0, false);
                pk = (unsigned)__builtin_amdgcn_cvt_pk_fp8_f32(acc[2][reg] + b2, acc[3][reg] + b3, (int)pk, true);
                *(unsigned*)(Hr8 + ((size_t)r << 8) + (s * 16 + n15) * 4) = pk;
            }
        }
    }

    // ---- Rres: tile 8 ----
    {
        bf16x8 bfr[4][4];
#pragma unroll
        for (int ks = 0; ks < 4; ++ks)
#pragma unroll
            for (int j = 0; j < 4; ++j)
                bfr[ks][j] = *(const bf16x8*)(Btg2 + ((8 * 16 + j * 4 + ks) << 9) + lofs);
        f32x4 acc[4] = {};
#pragma unroll
        for (int ks = 0; ks < 4; ++ks)
#pragma unroll
            for (int j = 0; j < 4; ++j)
                acc[j] = __builtin_amdgcn_mfma_f32_16x16x32_bf16(af[ks], bfr[ks][j], acc[j], 0, 0, 0);
#pragma unroll
        for (int reg = 0; reg < 4; ++reg) {
            int r = m0 + quad * 4 + reg;
            if (full || r < N) {
#pragma unroll
                for (int j = 0; j < 4; ++j)
                    Rres[(size_t)r * OUTD + j * 16 + n15] = f2bf(acc[j][reg] + res_b[j * 16 + n15]);
            }
        }
    }

    // ---- el/er: tile 9 ----
    {
        bf16x8 b4[4];
#pragma unroll
        for (int ks = 0; ks < 4; ++ks)
            b4[ks] = *(const bf16x8*)(Btg2 + ((9 * 16 + ks) << 9) + lofs);
        f32x4 acc2 = {};
#pragma unroll
        for (int ks = 0; ks < 4; ++ks)
            acc2 = __builtin_amdgcn_mfma_f32_16x16x32_bf16(af[ks], b4[ks], acc2, 0, 0, 0);
#pragma unroll
        for (int reg = 0; reg < 4; ++reg) {
            int r = m0 + quad * 4 + reg;
            if ((full || r < N) && n15 < 8) {
                float v = acc2[reg];
                if (n15 < 4) el[(size_t)r * 4 + n15] = v;
                else         er[(size_t)r * 4 + (n15 - 4)] = v;
            }
        }
    }
}

// ============ scanA: per-256 chunk exclusive scans + chunk sums ============
__global__ __launch_bounds__(256) void scanA_kernel(const int* __restrict__ degree,
                                                    int* __restrict__ excl,
                                                    int* __restrict__ blocksum, int N) {
    __shared__ int sm[256];
    int t = threadIdx.x;
    int i = blockIdx.x * 256 + t;
    int d = (i < N) ? degree[i] : 0;
    sm[t] = d; __syncthreads();
    for (int off = 1; off < 256; off <<= 1) {
        int v = (t >= off) ? sm[t - off] : 0;
        __syncthreads();
        sm[t] += v;
        __syncthreads();
    }
    if (i < N) excl[i] = sm[t] - d;
    if (t == 255) blocksum[blockIdx.x] = sm[255];
}

// ============ aggregation: 2-edges/iter half-wave bpermute broadcast; fused BN ============
// Lane layout: half = lane>>5 selects edge (A/B), hl = lane&31 owns dims {2hl, 2hl+1}.
// Per 2 edges: 1 bperm-addr add + 5 ds_bpermute + 1 addr add + 1 dwordx2 load + 4 cvt + 8 FMA
// (~7 VALU inst/edge vs 13 in the readlane version; no tail loops).
__global__ __launch_bounds__(256) void agg_kernel(
    const unsigned char* __restrict__ Hh8, const unsigned char* __restrict__ Hr8,
    const unsigned short* __restrict__ Rres, const float* __restrict__ el,
    const float* __restrict__ er,
    const int* __restrict__ excl, const int* __restrict__ base,
    const unsigned* __restrict__ usrc_sorted,
    const float* __restrict__ conv_w, const float* __restrict__ conv_b,
    float* __restrict__ y, float* __restrict__ bnsum8, float* __restrict__ bnsq8,
    int N, int E)
{
    __shared__ float smA[256], smB[256], sqA[256], sqB[256];
    int t = threadIdx.x;
    int wave = t >> 6, lane = t & 63;
    int half = lane >> 5;
    int hl = lane & 31;
    int v = blockIdx.x * 4 + wave;

    float yv0 = 0.f, yv1 = 0.f;
    if (v < N) {
        int b  = excl[v] + base[v >> 8];
        int e2 = (v + 1 < N) ? (excl[v + 1] + base[(v + 1) >> 8]) : E;
        int deg = e2 - b;

        float4 rv = *(const float4*)(er + (size_t)v * 4);
        unsigned dimoff = (unsigned)(hl << 3);   // byte offset of this lane's dim pair
        int permbase = half << 2;                // bpermute addr: +4 selects edge B's lane
        float a00 = 0.f, a01 = 0.f, a02 = 0.f, a03 = 0.f;   // dim 2hl, heads 0..3
        float a10 = 0.f, a11 = 0.f, a12 = 0.f, a13 = 0.f;   // dim 2hl+1, heads 0..3
        float p0 = 0.f, p1 = 0.f, p2 = 0.f, p3 = 0.f;

        for (int i0 = 0; i0 < deg; i0 += 64) {
            int j = i0 + lane;
            unsigned ux = 0;
            float s0 = 0.f, s1 = 0.f, s2 = 0.f, s3 = 0.f;
            if (j < deg) {
                ux = usrc_sorted[b + j];
                float4 l = *(const float4*)(el + ((size_t)(ux >> 8)) * 4);   // L2-hot (800 KB)
                float x;
                x = l.x + rv.x; x = x > 0.f ? x : NEG_SLOPE * x; s0 = __expf(x);
                x = l.y + rv.y; x = x > 0.f ? x : NEG_SLOPE * x; s1 = __expf(x);
                x = l.z + rv.z; x = x > 0.f ? x : NEG_SLOPE * x; s2 = __expf(x);
                x = l.w + rv.w; x = x > 0.f ? x : NEG_SLOPE * x; s3 = __expf(x);
                p0 += s0; p1 += s1; p2 += s2; p3 += s3;
            }
            int cl = deg - i0; if (cl > 64) cl = 64;

            // lanes >= cl carry ux=0, s*=0 -> zero-weight contributions; no tails needed
#pragma unroll 4
            for (int jj = 0; jj < cl; jj += 2) {
                int pa = permbase + (jj << 2);
                unsigned uxp = (unsigned)__builtin_amdgcn_ds_bpermute(pa, (int)ux);
                float w0 = u2f((unsigned)__builtin_amdgcn_ds_bpermute(pa, (int)f2u(s0)));
                float w1 = u2f((unsigned)__builtin_amdgcn_ds_bpermute(pa, (int)f2u(s1)));
                float w2 = u2f((unsigned)__builtin_amdgcn_ds_bpermute(pa, (int)f2u(s2)));
                float w3 = u2f((unsigned)__builtin_amdgcn_ds_bpermute(pa, (int)f2u(s3)));
                uint2 g = *(const uint2*)(Hh8 + (size_t)(uxp + dimoff));
                f32x2 lo0 = __builtin_amdgcn_cvt_pk_f32_fp8(g.x, false);
                f32x2 hi0 = __builtin_amdgcn_cvt_pk_f32_fp8(g.x, true);
                f32x2 lo1 = __builtin_amdgcn_cvt_pk_f32_fp8(g.y, false);
                f32x2 hi1 = __builtin_amdgcn_cvt_pk_f32_fp8(g.y, true);
                a00 += w0 * lo0.x; a01 += w1 * lo0.y; a02 += w2 * hi0.x; a03 += w3 * hi0.y;
                a10 += w0 * lo1.x; a11 += w1 * lo1.y; a12 += w2 * hi1.x; a13 += w3 * hi1.y;
            }
        }
        // combine half-wave partials (each dim pair accumulated in both halves)
        a00 += __shfl_xor(a00, 32); a01 += __shfl_xor(a01, 32);
        a02 += __shfl_xor(a02, 32); a03 += __shfl_xor(a03, 32);
        a10 += __shfl_xor(a10, 32); a11 += __shfl_xor(a11, 32);
        a12 += __shfl_xor(a12, 32); a13 += __shfl_xor(a13, 32);
#pragma unroll
        for (int off = 1; off < 64; off <<= 1) {
            p0 += __shfl_xor(p0, off); p1 += __shfl_xor(p1, off);
            p2 += __shfl_xor(p2, off); p3 += __shfl_xor(p3, off);
        }
        float r0 = 1.f / (p0 + 1e-16f), r1 = 1.f / (p1 + 1e-16f);
        float r2 = 1.f / (p2 + 1e-16f), r3 = 1.f / (p3 + 1e-16f);

        uint2 hr = *(const uint2*)(Hr8 + ((size_t)v << 8) + hl * 8);
        f32x2 rlo0 = __builtin_amdgcn_cvt_pk_f32_fp8(hr.x, false);
        f32x2 rhi0 = __builtin_amdgcn_cvt_pk_f32_fp8(hr.x, true);
        f32x2 rlo1 = __builtin_amdgcn_cvt_pk_f32_fp8(hr.y, false);
        f32x2 rhi1 = __builtin_amdgcn_cvt_pk_f32_fp8(hr.y, true);
        unsigned rr = *(const unsigned*)(Rres + (size_t)v * OUTD + hl * 2);
        float res0 = bf2f((unsigned short)(rr & 0xffffu));
        float res1 = bf2f((unsigned short)(rr >> 16));
        float cb = conv_b[0];
        float cw0 = conv_w[0], cw1 = conv_w[1], cw2 = conv_w[2], cw3 = conv_w[3];
        float tt;
        yv0 = cb + (res0 > 0.f ? res0 : 0.f);
        tt = a00 * r0 + rlo0.x; tt = tt > 0.f ? tt : 0.f; yv0 += cw0 * tt;
        tt = a01 * r1 + rlo0.y; tt = tt > 0.f ? tt : 0.f; yv0 += cw1 * tt;
        tt = a02 * r2 + rhi0.x; tt = tt > 0.f ? tt : 0.f; yv0 += cw2 * tt;
        tt = a03 * r3 + rhi0.y; tt = tt > 0.f ? tt : 0.f; yv0 += cw3 * tt;
        yv1 = cb + (res1 > 0.f ? res1 : 0.f);
        tt = a10 * r0 + rlo1.x; tt = tt > 0.f ? tt : 0.f; yv1 += cw0 * tt;
        tt = a11 * r1 + rlo1.y; tt = tt > 0.f ? tt : 0.f; yv1 += cw1 * tt;
        tt = a12 * r2 + rhi1.x; tt = tt > 0.f ? tt : 0.f; yv1 += cw2 * tt;
        tt = a13 * r3 + rhi1.y; tt = tt > 0.f ? tt : 0.f; yv1 += cw3 * tt;
        if (half == 0)
            *(float2*)(y + (size_t)v * OUTD + hl * 2) = make_float2(yv0, yv1);
    }

    // ---- fused BN partials (half B duplicates -> zeroed) ----
    float c0 = (half == 0) ? yv0 : 0.f;
    float c1 = (half == 0) ? yv1 : 0.f;
    smA[t] = c0; smB[t] = c1; sqA[t] = c0 * c0; sqB[t] = c1 * c1;
    __syncthreads();
    if (t < 32) {
        float sA = smA[t] + smA[t + 64] + smA[t + 128] + smA[t + 192];
        float sB = smB[t] + smB[t + 64] + smB[t + 128] + smB[t + 192];
        float qA = sqA[t] + sqA[t + 64] + sqA[t + 128] + sqA[t + 192];
        float qB = sqB[t] + sqB[t + 64] + sqB[t + 128] + sqB[t + 192];
        int c = (blockIdx.x & 7) << 6;
        atomicAdd(bnsum8 + c + 2 * t,     sA);
        atomicAdd(bnsum8 + c + 2 * t + 1, sB);
        atomicAdd(bnsq8  + c + 2 * t,     qA);
        atomicAdd(bnsq8  + c + 2 * t + 1, qB);
    }
}

// ============ norm: fold 8-copy BN sums (per-block LDS) then normalize ============
__global__ __launch_bounds__(256) void norm_kernel(
    const float* __restrict__ y,
    const float* __restrict__ bnsum8, const float* __restrict__ bnsq8,
    const float* __restrict__ gamma, const float* __restrict__ beta,
    float* __restrict__ out, int total4, float invN) {
    __shared__ float scale[64], shift[64];
    int t = threadIdx.x;
    if (t < 64) {
        float s = 0.f, q = 0.f;
#pragma unroll
        for (int c = 0; c < 8; ++c) { s += bnsum8[c * 64 + t]; q += bnsq8[c * 64 + t]; }
        float mean = s * invN;
        float var = q * invN - mean * mean;
        float sc = gamma[t] * rsqrtf(var + BN_EPS);
        scale[t] = sc;
        shift[t] = beta[t] - mean * sc;
    }
    __syncthreads();
    int idx = blockIdx.x * blockDim.x + t;
    if (idx >= total4) return;
    float4 v = *(const float4*)(y + (size_t)idx * 4);
    int d = (idx * 4) & 63;
    float4 o;
    o.x = v.x * scale[d + 0] + shift[d + 0];
    o.y = v.y * scale[d + 1] + shift[d + 1];
    o.z = v.z * scale[d + 2] + shift[d + 2];
    o.w = v.w * scale[d + 3] + shift[d + 3];
    *(float4*)(out + (size_t)idx * 4) = o;
}

// ============ launch ============
extern "C" void kernel_launch(void* const* d_in, const int* in_sizes, int n_in,
                              void* d_out, int out_size, void* d_ws, size_t ws_size,
                              hipStream_t stream) {
    const float* node_feats = (const float*)d_in[0];
    const float* W_fc       = (const float*)d_in[1];
    const float* attn_l     = (const float*)d_in[2];
    const float* attn_r     = (const float*)d_in[3];
    const float* gat_res_w  = (const float*)d_in[4];
    const float* gat_bias   = (const float*)d_in[5];
    const float* conv_w     = (const float*)d_in[6];
    const float* conv_b     = (const float*)d_in[7];
    const float* res_w      = (const float*)d_in[8];
    const float* res_b      = (const float*)d_in[9];
    const float* bn_gamma   = (const float*)d_in[10];
    const float* bn_beta    = (const float*)d_in[11];
    const int*   src        = (const int*)d_in[12];
    const int*   dst        = (const int*)d_in[13];

    const int N = in_sizes[0] / IN_F;
    const int E = in_sizes[12];
    const int nb = (N + 255) / 256;
    const int T = (N + 15) / 16;
    const int Gblocks = (T + 3) / 4;

    char* ws = (char*)d_ws;
    size_t off = 0;
    auto alloc = [&](size_t bytes) -> void* {
        void* p = (void*)(ws + off);
        off += (bytes + 255) & ~(size_t)255;
        return p;
    };

    // --- zero zone ---
    int*   degree  = (int*)alloc((size_t)N * 4);
    float* bnsum8  = (float*)alloc(8 * 64 * 4);
    float* bnsq8   = (float*)alloc(8 * 64 * 4);
    size_t zero_bytes = off;
    // --- rest ---
    int*            rank        = (int*)alloc((size_t)E * 4);
    int*            excl        = (int*)alloc((size_t)N * 4);
    int*            blocksum    = (int*)alloc(256 * 4);
    int*            base        = (int*)alloc(256 * 4);
    unsigned*       usrc_sorted = (unsigned*)alloc((size_t)E * 4);
    unsigned short* Btg2        = (unsigned short*)alloc((size_t)10 * 16 * 512 * 2);
    unsigned char*  Hh8         = (unsigned char*)alloc((size_t)N * 256);
    unsigned char*  Hr8         = (unsigned char*)alloc((size_t)N * 256);
    unsigned short* Rres        = (unsigned short*)alloc((size_t)N * OUTD * 2);
    float*          el          = (float*)alloc((size_t)N * 4 * 4);
    float*          er          = (float*)alloc((size_t)N * 4 * 4);
    float*          y           = (float*)alloc((size_t)N * OUTD * 4);
    (void)ws_size; (void)n_in; (void)out_size;

    hipMemsetAsync(d_ws, 0, zero_bytes, stream);

    // 0. pack B weights (289 blocks) + hist role (HB blocks, last)
    k0_pack<<<289 + HB, 256, 0, stream>>>(W_fc, gat_res_w, res_w, attn_l, attn_r, Btg2,
                                          dst, degree, rank, E);
    // 1. scanA (chunk scans + chunk sums) — depends only on hist, runs before GEMM
    scanA_kernel<<<nb, 256, 0, stream>>>(degree, excl, blocksum, N);
    // 2. GEMM blocks first, scatter role blocks last (overlap CSR scatter with GEMM)
    k1_gemm<<<Gblocks + SB, 256, 0, stream>>>(node_feats, Btg2, gat_bias, res_b,
                                              src, dst, rank, excl, blocksum, base,
                                              usrc_sorted, Hh8, Hr8, Rres,
                                              el, er, N, E, Gblocks, nb);
    // 3. aggregation + scores + epilogue + fused BN partials
    agg_kernel<<<(N + 3) / 4, 256, 0, stream>>>(Hh8, Hr8, Rres, el, er, excl, base,
                                                usrc_sorted, conv_w, conv_b, y,
                                                bnsum8, bnsq8, N, E);
    // 4. norm (folds BN finalize)
    norm_kernel<<<(N * OUTD / 4 + 255) / 256, 256, 0, stream>>>(y, bnsum8, bnsq8,
                                                                bn_gamma, bn_beta, (float*)d_out,
                                                                N * OUTD / 4, 1.f / (float)N);
}

// Round 4
// 230.688 us; speedup vs baseline: 1.1338x; 1.1338x over previous
//
#include <hip/hip_runtime.h>

#define IN_F   128
#define OUTD   64
#define HOUT   256      // H*OUT
#define NEG_SLOPE 0.2f
#define BN_EPS 1e-5f
#define HB     1024     // histogram blocks — appended to k0 (pack blocks first)
#define SB     512      // scatter blocks — appended to k1 (GEMM blocks first, R10 pattern)

typedef __attribute__((ext_vector_type(8))) short bf16x8;
typedef __attribute__((ext_vector_type(4))) float f32x4;
typedef __attribute__((ext_vector_type(2))) float f32x2;

__device__ __forceinline__ unsigned short f2bf(float f) {
    union { float f; unsigned u; } v; v.f = f;
    unsigned r = (v.u + 0x7FFF + ((v.u >> 16) & 1)) >> 16;   // RNE
    return (unsigned short)r;
}
__device__ __forceinline__ float bf2f(unsigned short h) {
    union { unsigned u; float f; } v; v.u = ((unsigned)h) << 16;
    return v.f;
}
__device__ __forceinline__ float u2f(unsigned u) {
    union { unsigned u; float f; } v; v.u = u;
    return v.f;
}
__device__ __forceinline__ unsigned f2u(float f) {
    union { float f; unsigned u; } v; v.f = f;
    return v.u;
}

// fragment-order index for Btg2. Tiles (tt=0..9), j=0..3, ks=0..3, 16 cols (n15), 8 k (kk).
__device__ __forceinline__ int b2idx(int c, int k) {
    int tt, j;
    if (c < 256)      { tt = (c >> 4) & 3;                     j = c >> 6; }
    else if (c < 512) { int cc = c - 256; tt = 4 + ((cc >> 4) & 3); j = cc >> 6; }
    else if (c < 576) { int cc = c - 512; tt = 8;              j = cc >> 4; }
    else              { tt = 9;                                j = 0; }
    int n15 = c & 15;
    int ks = k >> 5, qd = (k >> 3) & 3, kk = k & 7;
    return ((((tt * 4 + j) * 4 + ks) * 64) + qd * 16 + n15) * 8 + kk;
}

// ============ K0: pack weights -> Btg2 (fragment-ordered bf16) + hist role ============
__global__ __launch_bounds__(256) void k0_pack(
    const float* __restrict__ W_fc, const float* __restrict__ W_gres,
    const float* __restrict__ W_res,
    const float* __restrict__ attn_l, const float* __restrict__ attn_r,
    unsigned short* __restrict__ Btg2,
    const int* __restrict__ dst, int* __restrict__ degree,
    int* __restrict__ rank, int E)
{
    int bid = blockIdx.x, t = threadIdx.x;
    if (bid < 288) {
        int idx = bid * 256 + t;          // c*128 + k, c < 576
        int c = idx >> 7, k = idx & 127;
        float v;
        if (c < 256)      v = W_fc[k * HOUT + c];
        else if (c < 512) v = W_gres[k * HOUT + (c - 256)];
        else              v = W_res[k * OUTD + (c - 512)];
        Btg2[b2idx(c, k)] = f2bf(v);
        return;
    }
    if (bid == 288) {
        for (int p = t; p < 512; p += 256) {
            int h = p >> 7, k = p & 127;
            float sl = 0.f, sr = 0.f;
            for (int d = 0; d < 64; ++d) {
                float wv = W_fc[k * HOUT + h * 64 + d];
                sl += wv * attn_l[h * 64 + d];
                sr += wv * attn_r[h * 64 + d];
            }
            Btg2[b2idx(576 + h, k)] = f2bf(sl);
            Btg2[b2idx(580 + h, k)] = f2bf(sr);
        }
        for (int p = t; p < 8 * 128; p += 256) {
            int c = 584 + (p >> 7), k = p & 127;
            Btg2[b2idx(c, k)] = 0;
        }
        return;
    }
    // ---- hist role: degree histogram + per-edge rank (independent of GEMM chain) ----
    int ht = (bid - 289) * 256 + t;
    for (int e = ht; e < E; e += HB * 256)
        rank[e] = atomicAdd(degree + dst[e], 1);
}

// ============ K1: GEMM blocks first, scatter blocks last (role-split) ============
__global__ __launch_bounds__(256) void k1_gemm(
    const float* __restrict__ A, const unsigned short* __restrict__ Btg2,
    const float* __restrict__ gat_bias, const float* __restrict__ res_b,
    const int* __restrict__ src, const int* __restrict__ dst,
    const int* __restrict__ rank, const int* __restrict__ excl,
    const int* __restrict__ blocksum, int* __restrict__ base,
    unsigned* __restrict__ usrc_sorted,
    unsigned char* __restrict__ Hh8, unsigned char* __restrict__ Hr8,
    unsigned short* __restrict__ Rres,
    float* __restrict__ el, float* __restrict__ er,
    int N, int E, int Gblocks, int nb)
{
    int t = threadIdx.x;

    if (blockIdx.x >= Gblocks) {
        // ---- scatter role (+inline scanB; block sb==0 persists base for agg) ----
        __shared__ int sm[256];
        __shared__ int base_lds[256];
        int sb = blockIdx.x - Gblocks;
        int d0 = (t < nb) ? blocksum[t] : 0;
        sm[t] = d0; __syncthreads();
        for (int off = 1; off < 256; off <<= 1) {
            int v = (t >= off) ? sm[t - off] : 0;
            __syncthreads();
            sm[t] += v;
            __syncthreads();
        }
        base_lds[t] = sm[t] - d0;
        if (sb == 0) base[t] = sm[t] - d0;   // persist for agg
        __syncthreads();
        for (int e = sb * 256 + t; e < E; e += SB * 256) {
            int d = dst[e];
            int p = excl[d] + base_lds[d >> 8] + rank[e];
            usrc_sorted[p] = ((unsigned)src[e] << 8) | (unsigned)(d & 3);   // low 2 bits: local node id
        }
        return;
    }

    int w = t >> 6, lane = t & 63, quad = lane >> 4, n15 = lane & 15;
    int gw = blockIdx.x * 4 + w;
    int T = (N + 15) / 16;
    if (gw >= T) return;

    int m0 = gw * 16;
    bool full = (m0 + 16 <= N);
    int lofs = (quad * 16 + n15) * 8;

    bf16x8 af[4];
    {
        int r = m0 + n15;
#pragma unroll
        for (int ks = 0; ks < 4; ++ks) {
            float4 v0 = make_float4(0.f, 0.f, 0.f, 0.f), v1 = v0;
            if (r < N) {
                const float* ap = A + (size_t)r * IN_F + ks * 32 + quad * 8;
                v0 = *(const float4*)ap;
                v1 = *(const float4*)(ap + 4);
            }
            bf16x8 o;
            o[0] = f2bf(v0.x); o[1] = f2bf(v0.y); o[2] = f2bf(v0.z); o[3] = f2bf(v0.w);
            o[4] = f2bf(v1.x); o[5] = f2bf(v1.y); o[6] = f2bf(v1.z); o[7] = f2bf(v1.w);
            af[ks] = o;
        }
    }

    // ---- Hh: tiles 0..3 (j = head). Phase-wide load hoist: 16 frags in flight. ----
#pragma unroll
    for (int s = 0; s < 4; ++s) {
        bf16x8 bfr[4][4];
#pragma unroll
        for (int ks = 0; ks < 4; ++ks)
#pragma unroll
            for (int j = 0; j < 4; ++j)
                bfr[ks][j] = *(const bf16x8*)(Btg2 + ((s * 16 + j * 4 + ks) << 9) + lofs);
        f32x4 acc[4] = {};
#pragma unroll
        for (int ks = 0; ks < 4; ++ks)
#pragma unroll
            for (int j = 0; j < 4; ++j)
                acc[j] = __builtin_amdgcn_mfma_f32_16x16x32_bf16(af[ks], bfr[ks][j], acc[j], 0, 0, 0);
#pragma unroll
        for (int reg = 0; reg < 4; ++reg) {
            int r = m0 + quad * 4 + reg;
            if (full || r < N) {
                unsigned pk = (unsigned)__builtin_amdgcn_cvt_pk_fp8_f32(acc[0][reg], acc[1][reg], 0, false);
                pk = (unsigned)__builtin_amdgcn_cvt_pk_fp8_f32(acc[2][reg], acc[3][reg], (int)pk, true);
                *(unsigned*)(Hh8 + ((size_t)r << 8) + (s * 16 + n15) * 4) = pk;
            }
        }
    }

    // ---- Hr: tiles 4..7 (j = head) + gat_bias ----
#pragma unroll
    for (int s = 0; s < 4; ++s) {
        bf16x8 bfr[4][4];
#pragma unroll
        for (int ks = 0; ks < 4; ++ks)
#pragma unroll
            for (int j = 0; j < 4; ++j)
                bfr[ks][j] = *(const bf16x8*)(Btg2 + (((4 + s) * 16 + j * 4 + ks) << 9) + lofs);
        f32x4 acc[4] = {};
#pragma unroll
        for (int ks = 0; ks < 4; ++ks)
#pragma unroll
            for (int j = 0; j < 4; ++j)
                acc[j] = __builtin_amdgcn_mfma_f32_16x16x32_bf16(af[ks], bfr[ks][j], acc[j], 0, 0, 0);
        float b0 = gat_bias[0 * 64 + s * 16 + n15];
        float b1 = gat_bias[1 * 64 + s * 16 + n15];
        float b2 = gat_bias[2 * 64 + s * 16 + n15];
        float b3 = gat_bias[3 * 64 + s * 16 + n15];
#pragma unroll
        for (int reg = 0; reg < 4; ++reg) {
            int r = m0 + quad * 4 + reg;
            if (full || r < N) {
                unsigned pk = (unsigned)__builtin_amdgcn_cvt_pk_fp8_f32(acc[0][reg] + b0, acc[1][reg] + b1, 0, false);
                pk = (unsigned)__builtin_amdgcn_cvt_pk_fp8_f32(acc[2][reg] + b2, acc[3][reg] + b3, (int)pk, true);
                *(unsigned*)(Hr8 + ((size_t)r << 8) + (s * 16 + n15) * 4) = pk;
            }
        }
    }

    // ---- Rres: tile 8 ----
    {
        bf16x8 bfr[4][4];
#pragma unroll
        for (int ks = 0; ks < 4; ++ks)
#pragma unroll
            for (int j = 0; j < 4; ++j)
                bfr[ks][j] = *(const bf16x8*)(Btg2 + ((8 * 16 + j * 4 + ks) << 9) + lofs);
        f32x4 acc[4] = {};
#pragma unroll
        for (int ks = 0; ks < 4; ++ks)
#pragma unroll
            for (int j = 0; j < 4; ++j)
                acc[j] = __builtin_amdgcn_mfma_f32_16x16x32_bf16(af[ks], bfr[ks][j], acc[j], 0, 0, 0);
#pragma unroll
        for (int reg = 0; reg < 4; ++reg) {
            int r = m0 + quad * 4 + reg;
            if (full || r < N) {
#pragma unroll
                for (int j = 0; j < 4; ++j)
                    Rres[(size_t)r * OUTD + j * 16 + n15] = f2bf(acc[j][reg] + res_b[j * 16 + n15]);
            }
        }
    }

    // ---- el/er: tile 9 ----
    {
        bf16x8 b4[4];
#pragma unroll
        for (int ks = 0; ks < 4; ++ks)
            b4[ks] = *(const bf16x8*)(Btg2 + ((9 * 16 + ks) << 9) + lofs);
        f32x4 acc2 = {};
#pragma unroll
        for (int ks = 0; ks < 4; ++ks)
            acc2 = __builtin_amdgcn_mfma_f32_16x16x32_bf16(af[ks], b4[ks], acc2, 0, 0, 0);
#pragma unroll
        for (int reg = 0; reg < 4; ++reg) {
            int r = m0 + quad * 4 + reg;
            if ((full || r < N) && n15 < 8) {
                float v = acc2[reg];
                if (n15 < 4) el[(size_t)r * 4 + n15] = v;
                else         er[(size_t)r * 4 + (n15 - 4)] = v;
            }
        }
    }
}

// ============ scanA: per-256 chunk exclusive scans + chunk sums ============
__global__ __launch_bounds__(256) void scanA_kernel(const int* __restrict__ degree,
                                                    int* __restrict__ excl,
                                                    int* __restrict__ blocksum, int N) {
    __shared__ int sm[256];
    int t = threadIdx.x;
    int i = blockIdx.x * 256 + t;
    int d = (i < N) ? degree[i] : 0;
    sm[t] = d; __syncthreads();
    for (int off = 1; off < 256; off <<= 1) {
        int v = (t >= off) ? sm[t - off] : 0;
        __syncthreads();
        sm[t] += v;
        __syncthreads();
    }
    if (i < N) excl[i] = sm[t] - d;
    if (t == 255) blocksum[blockIdx.x] = sm[255];
}

// ============ aggregation: 4 nodes/wave, readlane broadcast, LDS-atomic p; fused BN ============
// Wave owns nodes v0..v0+3 (contiguous sorted edge range). Score phase: ~all lanes useful.
// Edge's local node id rides in usrc low 2 bits; p[node][head] accumulated via ds_add_f32
// (LDS pipe, off the VALU). Broadcast loop: proven readlane batching + uniform switch.
__global__ __launch_bounds__(256) void agg_kernel(
    const unsigned char* __restrict__ Hh8, const unsigned char* __restrict__ Hr8,
    const unsigned short* __restrict__ Rres, const float* __restrict__ el,
    const float* __restrict__ er,
    const int* __restrict__ excl, const int* __restrict__ base,
    const unsigned* __restrict__ usrc_sorted,
    const float* __restrict__ conv_w, const float* __restrict__ conv_b,
    float* __restrict__ y, float* __restrict__ bnsum8, float* __restrict__ bnsq8,
    int N, int E)
{
    __shared__ float p_lds[4][4][4];    // [wave][node][head]
    __shared__ float smem[256];
    __shared__ float smem2[256];
    int t = threadIdx.x;
    int wave = t >> 6, lane = t & 63;
    int v0 = (blockIdx.x * 4 + wave) * 4;

    if (lane < 16) p_lds[wave][lane >> 2][lane & 3] = 0.f;

    float bn_s = 0.f, bn_q = 0.f;
    if (v0 < N) {
        int b = excl[v0] + base[v0 >> 8];
        int e2 = (v0 + 4 < N) ? (excl[v0 + 4] + base[(v0 + 4) >> 8]) : E;
        int deg = e2 - b;

        unsigned loff = (unsigned)(lane << 2);
        f32x4 a0 = {}, a1 = {}, a2 = {}, a3 = {};   // per-node accumulators (4 heads each)

        for (int i0 = 0; i0 < deg; i0 += 64) {
            int j = i0 + lane;
            unsigned ux = 0;
            float s0 = 0.f, s1 = 0.f, s2 = 0.f, s3 = 0.f;
            if (j < deg) {
                ux = usrc_sorted[b + j];
                int nid = (int)(ux & 3u);
                float4 l = *(const float4*)(el + ((size_t)(ux >> 8)) * 4);   // L2-hot
                float4 rv = *(const float4*)(er + (size_t)(v0 + nid) * 4);   // L1-hot (4 distinct)
                float x;
                x = l.x + rv.x; x = x > 0.f ? x : NEG_SLOPE * x; s0 = __expf(x);
                x = l.y + rv.y; x = x > 0.f ? x : NEG_SLOPE * x; s1 = __expf(x);
                x = l.z + rv.z; x = x > 0.f ? x : NEG_SLOPE * x; s2 = __expf(x);
                x = l.w + rv.w; x = x > 0.f ? x : NEG_SLOPE * x; s3 = __expf(x);
                atomicAdd(&p_lds[wave][nid][0], s0);
                atomicAdd(&p_lds[wave][nid][1], s1);
                atomicAdd(&p_lds[wave][nid][2], s2);
                atomicAdd(&p_lds[wave][nid][3], s3);
            }
            int cl = deg - i0; if (cl > 64) cl = 64;

#define CONSUME(UK, GK, IDX)                                                          \
            {                                                                         \
                float w0 = u2f((unsigned)__builtin_amdgcn_readlane((int)f2u(s0), (IDX))); \
                float w1 = u2f((unsigned)__builtin_amdgcn_readlane((int)f2u(s1), (IDX))); \
                float w2 = u2f((unsigned)__builtin_amdgcn_readlane((int)f2u(s2), (IDX))); \
                float w3 = u2f((unsigned)__builtin_amdgcn_readlane((int)f2u(s3), (IDX))); \
                f32x2 lo = __builtin_amdgcn_cvt_pk_f32_fp8((GK), false);              \
                f32x2 hi = __builtin_amdgcn_cvt_pk_f32_fp8((GK), true);               \
                switch ((UK) & 3u) {                                                  \
                case 0: a0[0] += w0 * lo.x; a0[1] += w1 * lo.y; a0[2] += w2 * hi.x; a0[3] += w3 * hi.y; break; \
                case 1: a1[0] += w0 * lo.x; a1[1] += w1 * lo.y; a1[2] += w2 * hi.x; a1[3] += w3 * hi.y; break; \
                case 2: a2[0] += w0 * lo.x; a2[1] += w1 * lo.y; a2[2] += w2 * hi.x; a2[3] += w3 * hi.y; break; \
                default: a3[0] += w0 * lo.x; a3[1] += w1 * lo.y; a3[2] += w2 * hi.x; a3[3] += w3 * hi.y; break; \
                }                                                                     \
            }

            int jj = 0;
            for (; jj + 3 < cl; jj += 4) {
                unsigned uk0 = (unsigned)__builtin_amdgcn_readlane((int)ux, jj + 0);
                unsigned uk1 = (unsigned)__builtin_amdgcn_readlane((int)ux, jj + 1);
                unsigned uk2 = (unsigned)__builtin_amdgcn_readlane((int)ux, jj + 2);
                unsigned uk3 = (unsigned)__builtin_amdgcn_readlane((int)ux, jj + 3);
                unsigned g0 = *(const unsigned*)(Hh8 + (size_t)(uk0 & ~255u) + loff);
                unsigned g1 = *(const unsigned*)(Hh8 + (size_t)(uk1 & ~255u) + loff);
                unsigned g2 = *(const unsigned*)(Hh8 + (size_t)(uk2 & ~255u) + loff);
                unsigned g3 = *(const unsigned*)(Hh8 + (size_t)(uk3 & ~255u) + loff);
                CONSUME(uk0, g0, jj + 0)
                CONSUME(uk1, g1, jj + 1)
                CONSUME(uk2, g2, jj + 2)
                CONSUME(uk3, g3, jj + 3)
            }
            for (; jj < cl; ++jj) {
                unsigned uk = (unsigned)__builtin_amdgcn_readlane((int)ux, jj);
                unsigned g = *(const unsigned*)(Hh8 + (size_t)(uk & ~255u) + loff);
                CONSUME(uk, g, jj)
            }
#undef CONSUME
        }

        // ---- epilogue: 4 nodes per wave ----
        float cb = conv_b[0];
        float cw0 = conv_w[0], cw1 = conv_w[1], cw2 = conv_w[2], cw3 = conv_w[3];
#define EPI(I, ACC)                                                                   \
        {                                                                             \
            int vv = v0 + (I);                                                        \
            if (vv < N) {                                                             \
                float4 pp = *(const float4*)&p_lds[wave][(I)][0];                     \
                float r0 = 1.f / (pp.x + 1e-16f), r1 = 1.f / (pp.y + 1e-16f);         \
                float r2 = 1.f / (pp.z + 1e-16f), r3 = 1.f / (pp.w + 1e-16f);         \
                unsigned hr = *(const unsigned*)(Hr8 + ((size_t)vv << 8) + loff);     \
                f32x2 rlo = __builtin_amdgcn_cvt_pk_f32_fp8(hr, false);               \
                f32x2 rhi = __builtin_amdgcn_cvt_pk_f32_fp8(hr, true);                \
                float resv = bf2f(Rres[(size_t)vv * OUTD + lane]);                    \
                float yv = cb + (resv > 0.f ? resv : 0.f);                            \
                float tt;                                                             \
                tt = ACC[0] * r0 + rlo.x; tt = tt > 0.f ? tt : 0.f; yv += cw0 * tt;   \
                tt = ACC[1] * r1 + rlo.y; tt = tt > 0.f ? tt : 0.f; yv += cw1 * tt;   \
                tt = ACC[2] * r2 + rhi.x; tt = tt > 0.f ? tt : 0.f; yv += cw2 * tt;   \
                tt = ACC[3] * r3 + rhi.y; tt = tt > 0.f ? tt : 0.f; yv += cw3 * tt;   \
                y[(size_t)vv * OUTD + lane] = yv;                                     \
                bn_s += yv; bn_q += yv * yv;                                          \
            }                                                                         \
        }
        EPI(0, a0)
        EPI(1, a1)
        EPI(2, a2)
        EPI(3, a3)
#undef EPI
    }

    // ---- fused BN partials: per-block LDS reduce -> 8-way split atomics ----
    smem[t] = bn_s;
    smem2[t] = bn_q;
    __syncthreads();
    if (t < 64) {
        float s = smem[t] + smem[t + 64] + smem[t + 128] + smem[t + 192];
        float q = smem2[t] + smem2[t + 64] + smem2[t + 128] + smem2[t + 192];
        int c = (blockIdx.x & 7) << 6;
        atomicAdd(bnsum8 + c + t, s);
        atomicAdd(bnsq8 + c + t, q);
    }
}

// ============ norm: fold 8-copy BN sums (per-block LDS) then normalize ============
__global__ __launch_bounds__(256) void norm_kernel(
    const float* __restrict__ y,
    const float* __restrict__ bnsum8, const float* __restrict__ bnsq8,
    const float* __restrict__ gamma, const float* __restrict__ beta,
    float* __restrict__ out, int total4, float invN) {
    __shared__ float scale[64], shift[64];
    int t = threadIdx.x;
    if (t < 64) {
        float s = 0.f, q = 0.f;
#pragma unroll
        for (int c = 0; c < 8; ++c) { s += bnsum8[c * 64 + t]; q += bnsq8[c * 64 + t]; }
        float mean = s * invN;
        float var = q * invN - mean * mean;
        float sc = gamma[t] * rsqrtf(var + BN_EPS);
        scale[t] = sc;
        shift[t] = beta[t] - mean * sc;
    }
    __syncthreads();
    int idx = blockIdx.x * blockDim.x + t;
    if (idx >= total4) return;
    float4 v = *(const float4*)(y + (size_t)idx * 4);
    int d = (idx * 4) & 63;
    float4 o;
    o.x = v.x * scale[d + 0] + shift[d + 0];
    o.y = v.y * scale[d + 1] + shift[d + 1];
    o.z = v.z * scale[d + 2] + shift[d + 2];
    o.w = v.w * scale[d + 3] + shift[d + 3];
    *(float4*)(out + (size_t)idx * 4) = o;
}

// ============ launch ============
extern "C" void kernel_launch(void* const* d_in, const int* in_sizes, int n_in,
                              void* d_out, int out_size, void* d_ws, size_t ws_size,
                              hipStream_t stream) {
    const float* node_feats = (const float*)d_in[0];
    const float* W_fc       = (const float*)d_in[1];
    const float* attn_l     = (const float*)d_in[2];
    const float* attn_r     = (const float*)d_in[3];
    const float* gat_res_w  = (const float*)d_in[4];
    const float* gat_bias   = (const float*)d_in[5];
    const float* conv_w     = (const float*)d_in[6];
    const float* conv_b     = (const float*)d_in[7];
    const float* res_w      = (const float*)d_in[8];
    const float* res_b      = (const float*)d_in[9];
    const float* bn_gamma   = (const float*)d_in[10];
    const float* bn_beta    = (const float*)d_in[11];
    const int*   src        = (const int*)d_in[12];
    const int*   dst        = (const int*)d_in[13];

    const int N = in_sizes[0] / IN_F;
    const int E = in_sizes[12];
    const int nb = (N + 255) / 256;
    const int T = (N + 15) / 16;
    const int Gblocks = (T + 3) / 4;

    char* ws = (char*)d_ws;
    size_t off = 0;
    auto alloc = [&](size_t bytes) -> void* {
        void* p = (void*)(ws + off);
        off += (bytes + 255) & ~(size_t)255;
        return p;
    };

    // --- zero zone ---
    int*   degree  = (int*)alloc((size_t)N * 4);
    float* bnsum8  = (float*)alloc(8 * 64 * 4);
    float* bnsq8   = (float*)alloc(8 * 64 * 4);
    size_t zero_bytes = off;
    // --- rest ---
    int*            rank        = (int*)alloc((size_t)E * 4);
    int*            excl        = (int*)alloc((size_t)N * 4);
    int*            blocksum    = (int*)alloc(256 * 4);
    int*            base        = (int*)alloc(256 * 4);
    unsigned*       usrc_sorted = (unsigned*)alloc((size_t)E * 4);
    unsigned short* Btg2        = (unsigned short*)alloc((size_t)10 * 16 * 512 * 2);
    unsigned char*  Hh8         = (unsigned char*)alloc((size_t)N * 256);
    unsigned char*  Hr8         = (unsigned char*)alloc((size_t)N * 256);
    unsigned short* Rres        = (unsigned short*)alloc((size_t)N * OUTD * 2);
    float*          el          = (float*)alloc((size_t)N * 4 * 4);
    float*          er          = (float*)alloc((size_t)N * 4 * 4);
    float*          y           = (float*)alloc((size_t)N * OUTD * 4);
    (void)ws_size; (void)n_in; (void)out_size;

    hipMemsetAsync(d_ws, 0, zero_bytes, stream);

    // 0. pack B weights (289 blocks) + hist role (HB blocks, last)
    k0_pack<<<289 + HB, 256, 0, stream>>>(W_fc, gat_res_w, res_w, attn_l, attn_r, Btg2,
                                          dst, degree, rank, E);
    // 1. scanA (chunk scans + chunk sums) — depends only on hist, runs before GEMM
    scanA_kernel<<<nb, 256, 0, stream>>>(degree, excl, blocksum, N);
    // 2. GEMM blocks first, scatter role blocks last (overlap CSR scatter with GEMM)
    k1_gemm<<<Gblocks + SB, 256, 0, stream>>>(node_feats, Btg2, gat_bias, res_b,
                                              src, dst, rank, excl, blocksum, base,
                                              usrc_sorted, Hh8, Hr8, Rres,
                                              el, er, N, E, Gblocks, nb);
    // 3. aggregation (4 nodes/wave) + scores + epilogue + fused BN partials
    agg_kernel<<<(N + 15) / 16, 256, 0, stream>>>(Hh8, Hr8, Rres, el, er, excl, base,
                                                  usrc_sorted, conv_w, conv_b, y,
                                                  bnsum8, bnsq8, N, E);
    // 4. norm (folds BN finalize)
    norm_kernel<<<(N * OUTD / 4 + 255) / 256, 256, 0, stream>>>(y, bnsum8, bnsq8,
                                                                bn_gamma, bn_beta, (float*)d_out,
                                                                N * OUTD / 4, 1.f / (float)N);
}

// Round 5
// 224.594 us; speedup vs baseline: 1.1645x; 1.0271x over previous
//
#include <hip/hip_runtime.h>

#define IN_F   128
#define OUTD   64
#define HOUT   256      // H*OUT
#define NEG_SLOPE 0.2f
#define BN_EPS 1e-5f
#define HISTB  256      // hist tail blocks in k1 (GEMM blocks first — R10-proven ordering)

typedef __attribute__((ext_vector_type(8))) short bf16x8;
typedef __attribute__((ext_vector_type(4))) float f32x4;
typedef __attribute__((ext_vector_type(2))) float f32x2;

__device__ __forceinline__ unsigned short f2bf(float f) {
    union { float f; unsigned u; } v; v.f = f;
    unsigned r = (v.u + 0x7FFF + ((v.u >> 16) & 1)) >> 16;   // RNE
    return (unsigned short)r;
}
__device__ __forceinline__ float bf2f(unsigned short h) {
    union { unsigned u; float f; } v; v.u = ((unsigned)h) << 16;
    return v.f;
}
__device__ __forceinline__ float u2f(unsigned u) {
    union { unsigned u; float f; } v; v.u = u;
    return v.f;
}
__device__ __forceinline__ unsigned f2u(float f) {
    union { float f; unsigned u; } v; v.f = f;
    return v.u;
}

// fragment-order index for Btg2. Tiles (tt=0..9), j=0..3, ks=0..3, 16 cols (n15), 8 k (kk).
__device__ __forceinline__ int b2idx(int c, int k) {
    int tt, j;
    if (c < 256)      { tt = (c >> 4) & 3;                     j = c >> 6; }
    else if (c < 512) { int cc = c - 256; tt = 4 + ((cc >> 4) & 3); j = cc >> 6; }
    else if (c < 576) { int cc = c - 512; tt = 8;              j = cc >> 4; }
    else              { tt = 9;                                j = 0; }
    int n15 = c & 15;
    int ks = k >> 5, qd = (k >> 3) & 3, kk = k & 7;
    return ((((tt * 4 + j) * 4 + ks) * 64) + qd * 16 + n15) * 8 + kk;
}

// ============ K0: pack weights -> Btg2 (fragment-ordered bf16) ============
__global__ __launch_bounds__(256) void k0_pack(
    const float* __restrict__ W_fc, const float* __restrict__ W_gres,
    const float* __restrict__ W_res,
    const float* __restrict__ attn_l, const float* __restrict__ attn_r,
    unsigned short* __restrict__ Btg2)
{
    int bid = blockIdx.x, t = threadIdx.x;
    if (bid < 288) {
        int idx = bid * 256 + t;          // c*128 + k, c < 576
        int c = idx >> 7, k = idx & 127;
        float v;
        if (c < 256)      v = W_fc[k * HOUT + c];
        else if (c < 512) v = W_gres[k * HOUT + (c - 256)];
        else              v = W_res[k * OUTD + (c - 512)];
        Btg2[b2idx(c, k)] = f2bf(v);
        return;
    }
    for (int p = t; p < 512; p += 256) {
        int h = p >> 7, k = p & 127;
        float sl = 0.f, sr = 0.f;
        for (int d = 0; d < 64; ++d) {
            float wv = W_fc[k * HOUT + h * 64 + d];
            sl += wv * attn_l[h * 64 + d];
            sr += wv * attn_r[h * 64 + d];
        }
        Btg2[b2idx(576 + h, k)] = f2bf(sl);
        Btg2[b2idx(580 + h, k)] = f2bf(sr);
    }
    for (int p = t; p < 8 * 128; p += 256) {
        int c = 584 + (p >> 7), k = p & 127;
        Btg2[b2idx(c, k)] = 0;
    }
}

// ============ K1: GEMM blocks first, hist blocks last (R0-proven overlap) ============
__global__ __launch_bounds__(256) void k1_gemm(
    const float* __restrict__ A, const unsigned short* __restrict__ Btg2,
    const float* __restrict__ gat_bias, const float* __restrict__ res_b,
    const int* __restrict__ dst, int* __restrict__ degree, int* __restrict__ rank,
    unsigned char* __restrict__ Hh8, unsigned char* __restrict__ Hr8,
    unsigned short* __restrict__ Rres,
    float* __restrict__ el, float* __restrict__ er,
    int N, int E, int Gblocks)
{
    int t = threadIdx.x;

    if (blockIdx.x >= Gblocks) {
        // ---- hist role: degree histogram + per-edge rank (independent of GEMM) ----
        int ht = (blockIdx.x - Gblocks) * 256 + t;
        for (int e = ht; e < E; e += HISTB * 256)
            rank[e] = atomicAdd(degree + dst[e], 1);
        return;
    }

    int w = t >> 6, lane = t & 63, quad = lane >> 4, n15 = lane & 15;
    int gw = blockIdx.x * 4 + w;
    int T = (N + 15) / 16;
    if (gw >= T) return;

    int m0 = gw * 16;
    bool full = (m0 + 16 <= N);
    int lofs = (quad * 16 + n15) * 8;

    bf16x8 af[4];
    {
        int r = m0 + n15;
#pragma unroll
        for (int ks = 0; ks < 4; ++ks) {
            float4 v0 = make_float4(0.f, 0.f, 0.f, 0.f), v1 = v0;
            if (r < N) {
                const float* ap = A + (size_t)r * IN_F + ks * 32 + quad * 8;
                v0 = *(const float4*)ap;
                v1 = *(const float4*)(ap + 4);
            }
            bf16x8 o;
            o[0] = f2bf(v0.x); o[1] = f2bf(v0.y); o[2] = f2bf(v0.z); o[3] = f2bf(v0.w);
            o[4] = f2bf(v1.x); o[5] = f2bf(v1.y); o[6] = f2bf(v1.z); o[7] = f2bf(v1.w);
            af[ks] = o;
        }
    }

    // ---- Hh: tiles 0..3 (j = head). Phase-wide load hoist: 16 frags in flight. ----
#pragma unroll
    for (int s = 0; s < 4; ++s) {
        bf16x8 bfr[4][4];
#pragma unroll
        for (int ks = 0; ks < 4; ++ks)
#pragma unroll
            for (int j = 0; j < 4; ++j)
                bfr[ks][j] = *(const bf16x8*)(Btg2 + ((s * 16 + j * 4 + ks) << 9) + lofs);
        f32x4 acc[4] = {};
#pragma unroll
        for (int ks = 0; ks < 4; ++ks)
#pragma unroll
            for (int j = 0; j < 4; ++j)
                acc[j] = __builtin_amdgcn_mfma_f32_16x16x32_bf16(af[ks], bfr[ks][j], acc[j], 0, 0, 0);
#pragma unroll
        for (int reg = 0; reg < 4; ++reg) {
            int r = m0 + quad * 4 + reg;
            if (full || r < N) {
                unsigned pk = (unsigned)__builtin_amdgcn_cvt_pk_fp8_f32(acc[0][reg], acc[1][reg], 0, false);
                pk = (unsigned)__builtin_amdgcn_cvt_pk_fp8_f32(acc[2][reg], acc[3][reg], (int)pk, true);
                *(unsigned*)(Hh8 + ((size_t)r << 8) + (s * 16 + n15) * 4) = pk;
            }
        }
    }

    // ---- Hr: tiles 4..7 (j = head) + gat_bias ----
#pragma unroll
    for (int s = 0; s < 4; ++s) {
        bf16x8 bfr[4][4];
#pragma unroll
        for (int ks = 0; ks < 4; ++ks)
#pragma unroll
            for (int j = 0; j < 4; ++j)
                bfr[ks][j] = *(const bf16x8*)(Btg2 + (((4 + s) * 16 + j * 4 + ks) << 9) + lofs);
        f32x4 acc[4] = {};
#pragma unroll
        for (int ks = 0; ks < 4; ++ks)
#pragma unroll
            for (int j = 0; j < 4; ++j)
                acc[j] = __builtin_amdgcn_mfma_f32_16x16x32_bf16(af[ks], bfr[ks][j], acc[j], 0, 0, 0);
        float b0 = gat_bias[0 * 64 + s * 16 + n15];
        float b1 = gat_bias[1 * 64 + s * 16 + n15];
        float b2 = gat_bias[2 * 64 + s * 16 + n15];
        float b3 = gat_bias[3 * 64 + s * 16 + n15];
#pragma unroll
        for (int reg = 0; reg < 4; ++reg) {
            int r = m0 + quad * 4 + reg;
            if (full || r < N) {
                unsigned pk = (unsigned)__builtin_amdgcn_cvt_pk_fp8_f32(acc[0][reg] + b0, acc[1][reg] + b1, 0, false);
                pk = (unsigned)__builtin_amdgcn_cvt_pk_fp8_f32(acc[2][reg] + b2, acc[3][reg] + b3, (int)pk, true);
                *(unsigned*)(Hr8 + ((size_t)r << 8) + (s * 16 + n15) * 4) = pk;
            }
        }
    }

    // ---- Rres: tile 8 ----
    {
        bf16x8 bfr[4][4];
#pragma unroll
        for (int ks = 0; ks < 4; ++ks)
#pragma unroll
            for (int j = 0; j < 4; ++j)
                bfr[ks][j] = *(const bf16x8*)(Btg2 + ((8 * 16 + j * 4 + ks) << 9) + lofs);
        f32x4 acc[4] = {};
#pragma unroll
        for (int ks = 0; ks < 4; ++ks)
#pragma unroll
            for (int j = 0; j < 4; ++j)
                acc[j] = __builtin_amdgcn_mfma_f32_16x16x32_bf16(af[ks], bfr[ks][j], acc[j], 0, 0, 0);
#pragma unroll
        for (int reg = 0; reg < 4; ++reg) {
            int r = m0 + quad * 4 + reg;
            if (full || r < N) {
#pragma unroll
                for (int j = 0; j < 4; ++j)
                    Rres[(size_t)r * OUTD + j * 16 + n15] = f2bf(acc[j][reg] + res_b[j * 16 + n15]);
            }
        }
    }

    // ---- el/er: tile 9 ----
    {
        bf16x8 b4[4];
#pragma unroll
        for (int ks = 0; ks < 4; ++ks)
            b4[ks] = *(const bf16x8*)(Btg2 + ((9 * 16 + ks) << 9) + lofs);
        f32x4 acc2 = {};
#pragma unroll
        for (int ks = 0; ks < 4; ++ks)
            acc2 = __builtin_amdgcn_mfma_f32_16x16x32_bf16(af[ks], b4[ks], acc2, 0, 0, 0);
#pragma unroll
        for (int reg = 0; reg < 4; ++reg) {
            int r = m0 + quad * 4 + reg;
            if ((full || r < N) && n15 < 8) {
                float v = acc2[reg];
                if (n15 < 4) el[(size_t)r * 4 + n15] = v;
                else         er[(size_t)r * 4 + (n15 - 4)] = v;
            }
        }
    }
}

// ============ scanA: per-256 chunk exclusive scans + chunk sums ============
__global__ __launch_bounds__(256) void scanA_kernel(const int* __restrict__ degree,
                                                    int* __restrict__ excl,
                                                    int* __restrict__ blocksum, int N) {
    __shared__ int sm[256];
    int t = threadIdx.x;
    int i = blockIdx.x * 256 + t;
    int d = (i < N) ? degree[i] : 0;
    sm[t] = d; __syncthreads();
    for (int off = 1; off < 256; off <<= 1) {
        int v = (t >= off) ? sm[t - off] : 0;
        __syncthreads();
        sm[t] += v;
        __syncthreads();
    }
    if (i < N) excl[i] = sm[t] - d;
    if (t == 255) blocksum[blockIdx.x] = sm[255];
}

// ============ scatter (+inline scanB; block 0 persists base for agg) ============
__global__ __launch_bounds__(256) void scatter_kernel(
    const int* __restrict__ src, const int* __restrict__ dst,
    const int* __restrict__ rank, const int* __restrict__ excl,
    const int* __restrict__ blocksum, int* __restrict__ base,
    unsigned* __restrict__ usrc_sorted, int E, int nb) {
    __shared__ int sm[256];
    __shared__ int base_lds[256];
    int t = threadIdx.x;
    int d0 = (t < nb) ? blocksum[t] : 0;
    sm[t] = d0; __syncthreads();
    for (int off = 1; off < 256; off <<= 1) {
        int v = (t >= off) ? sm[t - off] : 0;
        __syncthreads();
        sm[t] += v;
        __syncthreads();
    }
    base_lds[t] = sm[t] - d0;
    if (blockIdx.x == 0) base[t] = sm[t] - d0;   // persist for agg
    __syncthreads();

    int e = blockIdx.x * 256 + t;
    if (e >= E) return;
    int d = dst[e];
    int p = excl[d] + base_lds[d >> 8] + rank[e];
    usrc_sorted[p] = (unsigned)src[e] << 8;
}

// ============ aggregation: fp32-score readlane broadcast, 4x unrolled; fused BN ============
__global__ __launch_bounds__(256) void agg_kernel(
    const unsigned char* __restrict__ Hh8, const unsigned char* __restrict__ Hr8,
    const unsigned short* __restrict__ Rres, const float* __restrict__ el,
    const float* __restrict__ er,
    const int* __restrict__ excl, const int* __restrict__ base,
    const unsigned* __restrict__ usrc_sorted,
    const float* __restrict__ conv_w, const float* __restrict__ conv_b,
    float* __restrict__ y, float* __restrict__ bnsum8, float* __restrict__ bnsq8,
    int N, int E)
{
    __shared__ float smem[256];
    __shared__ float smem2[256];
    int t = threadIdx.x;
    int wave = t >> 6, lane = t & 63;
    int v = blockIdx.x * 4 + wave;

    float yv = 0.f;
    if (v < N) {
        int b  = excl[v] + base[v >> 8];
        int e2 = (v + 1 < N) ? (excl[v + 1] + base[(v + 1) >> 8]) : E;
        int deg = e2 - b;

        float4 rv = *(const float4*)(er + (size_t)v * 4);
        const unsigned char* hbase = Hh8 + lane * 4;
        float a0 = 0.f, a1 = 0.f, a2 = 0.f, a3 = 0.f;
        float p0 = 0.f, p1 = 0.f, p2 = 0.f, p3 = 0.f;

        for (int i0 = 0; i0 < deg; i0 += 64) {
            int j = i0 + lane;
            unsigned ux = 0;
            float s0 = 0.f, s1 = 0.f, s2 = 0.f, s3 = 0.f;
            if (j < deg) {
                ux = usrc_sorted[b + j];
                float4 l = *(const float4*)(el + ((size_t)(ux >> 8)) * 4);   // L2-hot (800 KB)
                float x;
                x = l.x + rv.x; x = x > 0.f ? x : NEG_SLOPE * x; s0 = __expf(x);
                x = l.y + rv.y; x = x > 0.f ? x : NEG_SLOPE * x; s1 = __expf(x);
                x = l.z + rv.z; x = x > 0.f ? x : NEG_SLOPE * x; s2 = __expf(x);
                x = l.w + rv.w; x = x > 0.f ? x : NEG_SLOPE * x; s3 = __expf(x);
                p0 += s0; p1 += s1; p2 += s2; p3 += s3;
            }
            int cl = deg - i0; if (cl > 64) cl = 64;
            int jj = 0;
            for (; jj + 3 < cl; jj += 4) {
                unsigned u_[4], hv[4];
                float w0[4], w1[4], w2[4], w3[4];
#pragma unroll
                for (int k = 0; k < 4; ++k) {
                    u_[k] = (unsigned)__builtin_amdgcn_readlane((int)ux, jj + k);
                    w0[k] = u2f((unsigned)__builtin_amdgcn_readlane((int)f2u(s0), jj + k));
                    w1[k] = u2f((unsigned)__builtin_amdgcn_readlane((int)f2u(s1), jj + k));
                    w2[k] = u2f((unsigned)__builtin_amdgcn_readlane((int)f2u(s2), jj + k));
                    w3[k] = u2f((unsigned)__builtin_amdgcn_readlane((int)f2u(s3), jj + k));
                }
#pragma unroll
                for (int k = 0; k < 4; ++k)
                    hv[k] = *(const unsigned*)(hbase + u_[k]);
#pragma unroll
                for (int k = 0; k < 4; ++k) {
                    f32x2 lo = __builtin_amdgcn_cvt_pk_f32_fp8(hv[k], false);
                    f32x2 hi = __builtin_amdgcn_cvt_pk_f32_fp8(hv[k], true);
                    a0 += w0[k] * lo.x;
                    a1 += w1[k] * lo.y;
                    a2 += w2[k] * hi.x;
                    a3 += w3[k] * hi.y;
                }
            }
            for (; jj < cl; ++jj) {
                unsigned uA = (unsigned)__builtin_amdgcn_readlane((int)ux, jj);
                float w0 = u2f((unsigned)__builtin_amdgcn_readlane((int)f2u(s0), jj));
                float w1 = u2f((unsigned)__builtin_amdgcn_readlane((int)f2u(s1), jj));
                float w2 = u2f((unsigned)__builtin_amdgcn_readlane((int)f2u(s2), jj));
                float w3 = u2f((unsigned)__builtin_amdgcn_readlane((int)f2u(s3), jj));
                unsigned hvA = *(const unsigned*)(hbase + uA);
                f32x2 lo = __builtin_amdgcn_cvt_pk_f32_fp8(hvA, false);
                f32x2 hi = __builtin_amdgcn_cvt_pk_f32_fp8(hvA, true);
                a0 += w0 * lo.x;
                a1 += w1 * lo.y;
                a2 += w2 * hi.x;
                a3 += w3 * hi.y;
            }
        }
#pragma unroll
        for (int off = 1; off < 64; off <<= 1) {
            p0 += __shfl_xor(p0, off); p1 += __shfl_xor(p1, off);
            p2 += __shfl_xor(p2, off); p3 += __shfl_xor(p3, off);
        }
        float r0 = 1.f / (p0 + 1e-16f), r1 = 1.f / (p1 + 1e-16f);
        float r2 = 1.f / (p2 + 1e-16f), r3 = 1.f / (p3 + 1e-16f);

        unsigned hr = *(const unsigned*)(Hr8 + ((size_t)v << 8) + lane * 4);
        f32x2 rlo = __builtin_amdgcn_cvt_pk_f32_fp8(hr, false);
        f32x2 rhi = __builtin_amdgcn_cvt_pk_f32_fp8(hr, true);
        float resv = bf2f(Rres[(size_t)v * OUTD + lane]);
        yv = conv_b[0] + (resv > 0.f ? resv : 0.f);
        float tt;
        tt = a0 * r0 + rlo.x; tt = tt > 0.f ? tt : 0.f; yv += conv_w[0] * tt;
        tt = a1 * r1 + rlo.y; tt = tt > 0.f ? tt : 0.f; yv += conv_w[1] * tt;
        tt = a2 * r2 + rhi.x; tt = tt > 0.f ? tt : 0.f; yv += conv_w[2] * tt;
        tt = a3 * r3 + rhi.y; tt = tt > 0.f ? tt : 0.f; yv += conv_w[3] * tt;
        y[(size_t)v * OUTD + lane] = yv;
    }

    // ---- fused BN partials: per-block LDS reduce -> 8-way split atomics ----
    smem[t] = yv;
    smem2[t] = yv * yv;
    __syncthreads();
    if (t < 64) {
        float s = smem[t] + smem[t + 64] + smem[t + 128] + smem[t + 192];
        float q = smem2[t] + smem2[t + 64] + smem2[t + 128] + smem2[t + 192];
        int c = (blockIdx.x & 7) << 6;
        atomicAdd(bnsum8 + c + t, s);
        atomicAdd(bnsq8 + c + t, q);
    }
}

// ============ norm: fold 8-copy BN sums (per-block LDS) then normalize ============
__global__ __launch_bounds__(256) void norm_kernel(
    const float* __restrict__ y,
    const float* __restrict__ bnsum8, const float* __restrict__ bnsq8,
    const float* __restrict__ gamma, const float* __restrict__ beta,
    float* __restrict__ out, int total4, float invN) {
    __shared__ float scale[64], shift[64];
    int t = threadIdx.x;
    if (t < 64) {
        float s = 0.f, q = 0.f;
#pragma unroll
        for (int c = 0; c < 8; ++c) { s += bnsum8[c * 64 + t]; q += bnsq8[c * 64 + t]; }
        float mean = s * invN;
        float var = q * invN - mean * mean;
        float sc = gamma[t] * rsqrtf(var + BN_EPS);
        scale[t] = sc;
        shift[t] = beta[t] - mean * sc;
    }
    __syncthreads();
    int idx = blockIdx.x * blockDim.x + t;
    if (idx >= total4) return;
    float4 v = *(const float4*)(y + (size_t)idx * 4);
    int d = (idx * 4) & 63;
    float4 o;
    o.x = v.x * scale[d + 0] + shift[d + 0];
    o.y = v.y * scale[d + 1] + shift[d + 1];
    o.z = v.z * scale[d + 2] + shift[d + 2];
    o.w = v.w * scale[d + 3] + shift[d + 3];
    *(float4*)(out + (size_t)idx * 4) = o;
}

// ============ launch ============
extern "C" void kernel_launch(void* const* d_in, const int* in_sizes, int n_in,
                              void* d_out, int out_size, void* d_ws, size_t ws_size,
                              hipStream_t stream) {
    const float* node_feats = (const float*)d_in[0];
    const float* W_fc       = (const float*)d_in[1];
    const float* attn_l     = (const float*)d_in[2];
    const float* attn_r     = (const float*)d_in[3];
    const float* gat_res_w  = (const float*)d_in[4];
    const float* gat_bias   = (const float*)d_in[5];
    const float* conv_w     = (const float*)d_in[6];
    const float* conv_b     = (const float*)d_in[7];
    const float* res_w      = (const float*)d_in[8];
    const float* res_b      = (const float*)d_in[9];
    const float* bn_gamma   = (const float*)d_in[10];
    const float* bn_beta    = (const float*)d_in[11];
    const int*   src        = (const int*)d_in[12];
    const int*   dst        = (const int*)d_in[13];

    const int N = in_sizes[0] / IN_F;
    const int E = in_sizes[12];
    const int nb = (N + 255) / 256;
    const int T = (N + 15) / 16;
    const int Gblocks = (T + 3) / 4;

    char* ws = (char*)d_ws;
    size_t off = 0;
    auto alloc = [&](size_t bytes) -> void* {
        void* p = (void*)(ws + off);
        off += (bytes + 255) & ~(size_t)255;
        return p;
    };

    // --- zero zone ---
    int*   degree  = (int*)alloc((size_t)N * 4);
    float* bnsum8  = (float*)alloc(8 * 64 * 4);
    float* bnsq8   = (float*)alloc(8 * 64 * 4);
    size_t zero_bytes = off;
    // --- rest ---
    int*            rank        = (int*)alloc((size_t)E * 4);
    int*            excl        = (int*)alloc((size_t)N * 4);
    int*            blocksum    = (int*)alloc(256 * 4);
    int*            base        = (int*)alloc(256 * 4);
    unsigned*       usrc_sorted = (unsigned*)alloc((size_t)E * 4);
    unsigned short* Btg2        = (unsigned short*)alloc((size_t)10 * 16 * 512 * 2);
    unsigned char*  Hh8         = (unsigned char*)alloc((size_t)N * 256);
    unsigned char*  Hr8         = (unsigned char*)alloc((size_t)N * 256);
    unsigned short* Rres        = (unsigned short*)alloc((size_t)N * OUTD * 2);
    float*          el          = (float*)alloc((size_t)N * 4 * 4);
    float*          er          = (float*)alloc((size_t)N * 4 * 4);
    float*          y           = (float*)alloc((size_t)N * OUTD * 4);
    (void)ws_size; (void)n_in; (void)out_size;

    hipMemsetAsync(d_ws, 0, zero_bytes, stream);

    // 0. pack B weights
    k0_pack<<<289, 256, 0, stream>>>(W_fc, gat_res_w, res_w, attn_l, attn_r, Btg2);
    // 1. GEMM blocks first, hist blocks last (hist hidden under GEMM — R0-proven)
    k1_gemm<<<Gblocks + HISTB, 256, 0, stream>>>(node_feats, Btg2, gat_bias, res_b,
                                                 dst, degree, rank, Hh8, Hr8, Rres,
                                                 el, er, N, E, Gblocks);
    // 2. scanA (chunk scans + chunk sums)
    scanA_kernel<<<nb, 256, 0, stream>>>(degree, excl, blocksum, N);
    // 3. scatter (+inline scanB; block 0 persists base)
    scatter_kernel<<<(E + 255) / 256, 256, 0, stream>>>(src, dst, rank, excl, blocksum,
                                                        base, usrc_sorted, E, nb);
    // 4. aggregation + scores + epilogue + fused BN partials
    agg_kernel<<<(N + 3) / 4, 256, 0, stream>>>(Hh8, Hr8, Rres, el, er, excl, base,
                                                usrc_sorted, conv_w, conv_b, y,
                                                bnsum8, bnsq8, N, E);
    // 5. norm (folds BN finalize)
    norm_kernel<<<(N * OUTD / 4 + 255) / 256, 256, 0, stream>>>(y, bnsum8, bnsq8,
                                                                bn_gamma, bn_beta, (float*)d_out,
                                                                N * OUTD / 4, 1.f / (float)N);
}